// Round 1
// baseline (209.070 us; speedup 1.0000x reference)
//
#include <hip/hip_runtime.h>
#include <cstddef>
#include <cstdint>

// Problem constants (fixed by reference file)
#define B_    256
#define V_    128000
#define T_    16
#define TOPK_ 100
#define TPB   1024
#define CAP   4096
#define NF4   (V_ / 4)    // 32000 float4 per row
#define NHIST 4096

__global__ void zero_out_kernel(float* o) {
    o[0] = 0.f; o[1] = 0.f; o[2] = 0.f;
}

// One block per row. Streams the row once (float4), collects candidates
// >= T0 into LDS, validates against TOP_K, bitonic-sorts, sums top-100.
// Exact histogram fallback if the speculative threshold fails.
__global__ __launch_bounds__(TPB) void row_kernel(
        const float* __restrict__ sparse,
        const int*   __restrict__ tids,
        float*       __restrict__ out) {
    __shared__ float    s_cand[CAP];
    __shared__ unsigned s_hist[NHIST];
    __shared__ int      s_ids[T_];
    __shared__ int      s_cnt;
    __shared__ int      s_bstar;
    __shared__ float    s_red[128];

    const int row = blockIdx.x;
    const int tid = threadIdx.x;
    const float* __restrict__ rp = sparse + (size_t)row * V_;

    if (tid < T_) s_ids[tid] = tids[row * T_ + tid];
    if (tid == 0) s_cnt = 0;
    __syncthreads();

    // ---- target loss + margin loss (threads 0..15, one gather each) ----
    if (tid < T_) {
        float x  = rp[s_ids[tid]];
        float tl = -logf(x + 1e-8f);
        float ml = fmaxf(1.0f - x, 0.0f);
        #pragma unroll
        for (int off = 8; off > 0; off >>= 1) {
            tl += __shfl_down(tl, off);
            ml += __shfl_down(ml, off);
        }
        if (tid == 0) {
            atomicAdd(out + 0, tl * (1.0f / (B_ * T_)));
            atomicAdd(out + 1, ml * (1.0f / (B_ * T_)));
        }
    }

    // ---- streaming pass: collect candidates >= T0 (excluding targets) ----
    const float4* rp4 = (const float4*)rp;
    const float T0 = 0.996f;   // speculative: expected ~512 candidates/row
    for (int i = tid; i < NF4; i += TPB) {
        float4 v = rp4[i];
        int col = i << 2;
        float xs[4] = {v.x, v.y, v.z, v.w};
        #pragma unroll
        for (int c = 0; c < 4; ++c) {
            float x = xs[c];
            if (x >= T0) {
                int cc = col + c;
                bool is_t = false;
                #pragma unroll
                for (int j = 0; j < T_; ++j) is_t |= (cc == s_ids[j]);
                if (!is_t) {
                    int k = atomicAdd(&s_cnt, 1);
                    if (k < CAP) s_cand[k] = x;
                }
            }
        }
    }
    __syncthreads();

    int cnt = s_cnt;

    // ---- exact fallback (never triggered for uniform data, but correct) ----
    if (cnt < TOPK_ || cnt > CAP) {
        for (int i = tid; i < NHIST; i += TPB) s_hist[i] = 0u;
        __syncthreads();
        for (int i = tid; i < NF4; i += TPB) {
            float4 v = rp4[i];
            float xs[4] = {v.x, v.y, v.z, v.w};
            #pragma unroll
            for (int c = 0; c < 4; ++c) {
                int b = (int)(xs[c] * (float)NHIST);
                b = min(max(b, 0), NHIST - 1);
                atomicAdd(&s_hist[b], 1u);
            }
        }
        __syncthreads();
        if (tid == 0) {
            // remove unique target columns from the histogram
            for (int j = 0; j < T_; ++j) {
                int id = s_ids[j];
                bool dup = false;
                for (int q = 0; q < j; ++q) dup = dup || (s_ids[q] == id);
                if (!dup) {
                    int b = (int)(rp[id] * (float)NHIST);
                    b = min(max(b, 0), NHIST - 1);
                    s_hist[b]--;
                }
            }
            int acc = 0, b = NHIST - 1;
            for (; b >= 0; --b) {
                acc += (int)s_hist[b];
                if (acc >= TOPK_) break;
            }
            s_bstar = max(b, 0);
            s_cnt = 0;
        }
        __syncthreads();
        int bstar = s_bstar;
        for (int i = tid; i < NF4; i += TPB) {
            float4 v = rp4[i];
            int col = i << 2;
            float xs[4] = {v.x, v.y, v.z, v.w};
            #pragma unroll
            for (int c = 0; c < 4; ++c) {
                float x = xs[c];
                int b = (int)(x * (float)NHIST);
                b = min(max(b, 0), NHIST - 1);
                if (b >= bstar) {
                    int cc = col + c;
                    bool is_t = false;
                    #pragma unroll
                    for (int j = 0; j < T_; ++j) is_t |= (cc == s_ids[j]);
                    if (!is_t) {
                        int k = atomicAdd(&s_cnt, 1);
                        if (k < CAP) s_cand[k] = x;
                    }
                }
            }
        }
        __syncthreads();
        cnt = min(s_cnt, CAP);
    }

    // ---- pad to pow2 and bitonic sort ascending (pads = -inf -> at front) ----
    int n2 = 128;
    while (n2 < cnt) n2 <<= 1;           // n2 <= CAP (pow2)
    for (int i = cnt + tid; i < n2; i += TPB) s_cand[i] = -1e30f;
    __syncthreads();

    for (int k = 2; k <= n2; k <<= 1) {
        for (int j = k >> 1; j > 0; j >>= 1) {
            for (int i = tid; i < n2; i += TPB) {
                int p = i ^ j;
                if (p > i) {
                    float a = s_cand[i], b = s_cand[p];
                    bool asc = ((i & k) == 0);
                    if (asc ? (a > b) : (a < b)) {
                        s_cand[i] = b; s_cand[p] = a;
                    }
                }
            }
            __syncthreads();
        }
    }

    // ---- sum the top-100 (largest are at the tail after ascending sort) ----
    if (tid < 128) {
        float v = (tid < TOPK_) ? s_cand[n2 - 1 - tid] : 0.f;
        s_red[tid] = v;
    }
    __syncthreads();
    #pragma unroll
    for (int off = 64; off > 0; off >>= 1) {
        if (tid < off) s_red[tid] += s_red[tid + off];
        __syncthreads();
    }
    if (tid == 0) atomicAdd(out + 2, s_red[0] * (1.0f / (B_ * TOPK_)));
}

extern "C" void kernel_launch(void* const* d_in, const int* in_sizes, int n_in,
                              void* d_out, int out_size, void* d_ws, size_t ws_size,
                              hipStream_t stream) {
    const float* sparse = (const float*)d_in[0];
    const int*   tids   = (const int*)d_in[1];
    float*       out    = (float*)d_out;

    zero_out_kernel<<<1, 1, 0, stream>>>(out);
    row_kernel<<<B_, TPB, 0, stream>>>(sparse, tids, out);
}